// Round 1
// baseline (1453.470 us; speedup 1.0000x reference)
//
#include <hip/hip_runtime.h>
#include <hip/hip_bf16.h>

#define NN 80000
#define NE 1280000
#define HID 64
#define NL 4
#define NG 256

__device__ __forceinline__ float wave_sum(float v) {
    for (int off = 32; off; off >>= 1) v += __shfl_xor(v, off, 64);
    return v;
}

// ---------------- CSR build ----------------
__global__ void k_count(const int* __restrict__ dst, int* __restrict__ cnt) {
    int e = blockIdx.x * 256 + threadIdx.x;
    if (e < NE) atomicAdd(&cnt[dst[e]], 1);
}

// inclusive scan of 256-elem chunks; writes chunk-scanned values to out, chunk totals to bsum
__global__ void k_scan1(const int* __restrict__ in, int* __restrict__ out,
                        int* __restrict__ bsum, int n) {
    __shared__ int ws[4];
    int i = blockIdx.x * 256 + threadIdx.x;
    int v = (i < n) ? in[i] : 0;
    int lane = threadIdx.x & 63, w = threadIdx.x >> 6;
    for (int off = 1; off < 64; off <<= 1) {
        int t = __shfl_up(v, off, 64);
        if (lane >= off) v += t;
    }
    if (lane == 63) ws[w] = v;
    __syncthreads();
    if (threadIdx.x == 0) {
        int acc = 0;
        for (int k = 0; k < 4; k++) { int t = ws[k]; ws[k] = acc; acc += t; }
    }
    __syncthreads();
    v += ws[w];
    if (i < n) out[i] = v;
    if (threadIdx.x == 255) bsum[blockIdx.x] = v;
}

// single-block inclusive scan over nb elements in place
__global__ void k_scan2(int* __restrict__ bsum, int nb) {
    __shared__ int ws[4];
    __shared__ int carry;
    if (threadIdx.x == 0) carry = 0;
    __syncthreads();
    for (int base = 0; base < nb; base += 256) {
        int i = base + threadIdx.x;
        int v = (i < nb) ? bsum[i] : 0;
        int lane = threadIdx.x & 63, w = threadIdx.x >> 6;
        for (int off = 1; off < 64; off <<= 1) {
            int t = __shfl_up(v, off, 64);
            if (lane >= off) v += t;
        }
        if (lane == 63) ws[w] = v;
        __syncthreads();
        if (threadIdx.x == 0) {
            int acc = carry;
            for (int k = 0; k < 4; k++) { int t = ws[k]; ws[k] = acc; acc += t; }
            carry = acc;
        }
        __syncthreads();
        v += ws[w];
        if (i < nb) bsum[i] = v;
        __syncthreads();
    }
}

// rowptr[1+i] += block offset; rowptr[0]=0   (rowptr+1 already holds chunk-scanned counts)
__global__ void k_scan3(int* __restrict__ rowptr, const int* __restrict__ bsum, int n) {
    int i = blockIdx.x * 256 + threadIdx.x;
    if (i < n) {
        int off = (blockIdx.x > 0) ? bsum[blockIdx.x - 1] : 0;
        rowptr[1 + i] += off;
    }
    if (i == 0 && blockIdx.x == 0) rowptr[0] = 0;
}

__global__ void k_fill(const int* __restrict__ src, const int* __restrict__ dst,
                       const int* __restrict__ eattr, const int* __restrict__ rowptr,
                       int* __restrict__ wofs, int2* __restrict__ csr) {
    int e = blockIdx.x * 256 + threadIdx.x;
    if (e >= NE) return;
    int d = dst[e];
    int pos = rowptr[d] + atomicAdd(&wofs[d], 1);
    int a0 = eattr[e * 3], a1 = eattr[e * 3 + 1], a2 = eattr[e * 3 + 2];
    csr[pos] = make_int2(src[e], a0 + a1 * 10 + a2 * 100);
}

// ---------------- encoders ----------------
__global__ void k_comb(const float* __restrict__ bond_emb, float* __restrict__ comb) {
    int wid = (blockIdx.x * 256 + threadIdx.x) >> 6;
    int lane = threadIdx.x & 63;
    if (wid >= 1000) return;
    int a0 = wid % 10, a1 = (wid / 10) % 10, a2 = wid / 100;
    comb[wid * 64 + lane] = bond_emb[a0 * 64 + lane] +
                            bond_emb[(10 + a1) * 64 + lane] +
                            bond_emb[(20 + a2) * 64 + lane];
}

__global__ void k_atom(const int* __restrict__ x, const float* __restrict__ atom_emb,
                       float* __restrict__ xn) {
    int wid = (blockIdx.x * 256 + threadIdx.x) >> 6;
    int lane = threadIdx.x & 63;
    if (wid >= NN) return;
    float acc = 0.f;
#pragma unroll
    for (int f = 0; f < 9; f++) {
        int idx = x[wid * 9 + f] + f * 100;
        acc += atom_emb[idx * 64 + lane];
    }
    xn[wid * 64 + lane] = acc;
}

// ---------------- per-layer ----------------
__global__ void k_prenorm(const float* __restrict__ cur, const float* __restrict__ g,
                          const float* __restrict__ b, float* __restrict__ hh) {
    int wid = (blockIdx.x * 256 + threadIdx.x) >> 6;
    int lane = threadIdx.x & 63;
    if (wid >= NN) return;
    float v = cur[(long)wid * 64 + lane];
    float mu = wave_sum(v) * (1.f / 64.f);
    float d = v - mu;
    float var = wave_sum(d * d) * (1.f / 64.f);
    float y = d * rsqrtf(var + 1e-5f) * g[lane] + b[lane];
    hh[(long)wid * 64 + lane] = fmaxf(y, 0.f);
}

// fused: online-softmax edge aggregation + root add + MLP(64->128->LN->ReLU->64) + residual
__global__ __launch_bounds__(256) void k_conv(
    const float* __restrict__ hin, const int* __restrict__ rowptr,
    const int2* __restrict__ csr, const float* __restrict__ comb,
    const float* __restrict__ t, int l,
    const float* __restrict__ W1, const float* __restrict__ b1,
    const float* __restrict__ g1, const float* __restrict__ bb1,
    const float* __restrict__ W2, const float* __restrict__ b2,
    float* __restrict__ cur, int residual) {
    int wid = (blockIdx.x * 256 + threadIdx.x) >> 6;
    int lane = threadIdx.x & 63;
    if (wid >= NN) return;
    float tl = t[l];
    int rs = rowptr[wid], re = rowptr[wid + 1];
    float mx = -INFINITY, den = 0.f, num = 0.f;
    for (int p = rs; p < re; ++p) {
        int2 sc = csr[p];
        float h = hin[(long)sc.x * 64 + lane];
        float ea = comb[sc.y * 64 + lane];
        float msg = fmaxf(h + ea, 0.f) + 1e-7f;
        float m = msg * tl;
        if (m > mx) {
            float s = __expf(mx - m);
            den *= s; num *= s; mx = m;
        }
        float e = __expf(m - mx);
        den += e;
        num += e * msg;
    }
    float o = num / (den + 1e-16f) + hin[(long)wid * 64 + lane];

    const float* W1l = W1 + (long)l * 64 * 128;
    const float* W2l = W2 + (long)l * 128 * 64;
    float a0 = b1[l * 128 + lane];
    float a1 = b1[l * 128 + 64 + lane];
    for (int k = 0; k < 64; ++k) {
        float ok = __shfl(o, k, 64);
        a0 = fmaf(ok, W1l[k * 128 + lane], a0);
        a1 = fmaf(ok, W1l[k * 128 + 64 + lane], a1);
    }
    float mu = wave_sum(a0 + a1) * (1.f / 128.f);
    float d0 = a0 - mu, d1 = a1 - mu;
    float var = wave_sum(d0 * d0 + d1 * d1) * (1.f / 128.f);
    float r = rsqrtf(var + 1e-5f);
    float m0 = fmaxf(d0 * r * g1[l * 128 + lane] + bb1[l * 128 + lane], 0.f);
    float m1 = fmaxf(d1 * r * g1[l * 128 + 64 + lane] + bb1[l * 128 + 64 + lane], 0.f);
    float acc = b2[l * 64 + lane];
    for (int j = 0; j < 64; ++j) {
        float v0 = __shfl(m0, j, 64);
        float v1 = __shfl(m1, j, 64);
        acc = fmaf(v0, W2l[j * 64 + lane], acc);
        acc = fmaf(v1, W2l[(j + 64) * 64 + lane], acc);
    }
    long oi = (long)wid * 64 + lane;
    cur[oi] = (residual ? cur[oi] : 0.f) + acc;
}

// ---------------- pooling ----------------
__global__ void k_pool(const float* __restrict__ cur, const int* __restrict__ batch,
                       const float* __restrict__ g, const float* __restrict__ b,
                       float* __restrict__ sums, float* __restrict__ cnt) {
    int wid = (blockIdx.x * 256 + threadIdx.x) >> 6;
    int lane = threadIdx.x & 63;
    if (wid >= NN) return;
    float v = cur[(long)wid * 64 + lane];
    float mu = wave_sum(v) * (1.f / 64.f);
    float d = v - mu;
    float var = wave_sum(d * d) * (1.f / 64.f);
    float y = fmaxf(d * rsqrtf(var + 1e-5f) * g[lane] + b[lane], 0.f);
    int gi = batch[wid];
    atomicAdd(&sums[gi * 64 + lane], y);
    if (lane == 0) atomicAdd(&cnt[gi], 1.f);
}

__global__ void k_final(const float* __restrict__ sums, const float* __restrict__ cnt,
                        float* __restrict__ out) {
    int i = blockIdx.x * 256 + threadIdx.x;
    if (i < NG * 64) out[i] = sums[i] / fmaxf(cnt[i >> 6], 1.f);
}

extern "C" void kernel_launch(void* const* d_in, const int* in_sizes, int n_in,
                              void* d_out, int out_size, void* d_ws, size_t ws_size,
                              hipStream_t stream) {
    (void)in_sizes; (void)n_in; (void)out_size; (void)ws_size;
    const int* x         = (const int*)d_in[0];
    const int* edge_attr = (const int*)d_in[1];
    const int* src       = (const int*)d_in[2];
    const int* dst       = src + NE;
    const int* batch     = (const int*)d_in[3];
    const float* atom_emb = (const float*)d_in[4];
    const float* bond_emb = (const float*)d_in[5];
    const float* t        = (const float*)d_in[6];
    const float* W1       = (const float*)d_in[7];
    const float* b1       = (const float*)d_in[8];
    const float* g1       = (const float*)d_in[9];
    const float* bb1      = (const float*)d_in[10];
    const float* W2       = (const float*)d_in[11];
    const float* b2       = (const float*)d_in[12];
    const float* norm_g   = (const float*)d_in[13];
    const float* norm_b   = (const float*)d_in[14];
    float* out = (float*)d_out;

    size_t off = 0;
    auto alloc = [&](size_t bytes) {
        void* p = (char*)d_ws + off;
        off += (bytes + 255) & ~(size_t)255;
        return p;
    };
    int*   count  = (int*)alloc((size_t)NN * 4);
    int*   wofs   = (int*)alloc((size_t)NN * 4);
    int*   rowptr = (int*)alloc((size_t)(NN + 1) * 4);
    int*   bsum   = (int*)alloc(4096);
    int2*  csr    = (int2*)alloc((size_t)NE * 8);
    float* comb   = (float*)alloc(1000 * 64 * 4);
    float* xn     = (float*)alloc((size_t)NN * 64 * 4);
    float* hh     = (float*)alloc((size_t)NN * 64 * 4);
    float* cur    = (float*)alloc((size_t)NN * 64 * 4);
    float* sums   = (float*)alloc((size_t)NG * 64 * 4);
    float* cnt    = (float*)alloc((size_t)NG * 4);

    hipMemsetAsync(count, 0, (size_t)NN * 4, stream);
    hipMemsetAsync(wofs, 0, (size_t)NN * 4, stream);
    hipMemsetAsync(sums, 0, (size_t)NG * 64 * 4, stream);
    hipMemsetAsync(cnt, 0, (size_t)NG * 4, stream);

    const int EB = (NE + 255) / 256;          // 5000
    const int SB = (NN + 255) / 256;          // 313
    const int WB = (NN * 64 + 255) / 256;     // 20000 (wave-per-node blocks)

    k_count<<<EB, 256, 0, stream>>>(dst, count);
    k_scan1<<<SB, 256, 0, stream>>>(count, rowptr + 1, bsum, NN);
    k_scan2<<<1, 256, 0, stream>>>(bsum, SB);
    k_scan3<<<SB, 256, 0, stream>>>(rowptr, bsum, NN);
    k_fill<<<EB, 256, 0, stream>>>(src, dst, edge_attr, rowptr, wofs, csr);
    k_comb<<<(1000 * 64 + 255) / 256, 256, 0, stream>>>(bond_emb, comb);
    k_atom<<<WB, 256, 0, stream>>>(x, atom_emb, xn);

    // layer 0: cur = genconv(xn, 0)
    k_conv<<<WB, 256, 0, stream>>>(xn, rowptr, csr, comb, t, 0,
                                   W1, b1, g1, bb1, W2, b2, cur, 0);
    // layers 1..3: cur += genconv(relu(ln(cur, norm[l])), l)
    for (int l = 1; l < NL; ++l) {
        k_prenorm<<<WB, 256, 0, stream>>>(cur, norm_g + l * 64, norm_b + l * 64, hh);
        k_conv<<<WB, 256, 0, stream>>>(hh, rowptr, csr, comb, t, l,
                                       W1, b1, g1, bb1, W2, b2, cur, 1);
    }
    k_pool<<<WB, 256, 0, stream>>>(cur, batch, norm_g, norm_b, sums, cnt);
    k_final<<<(NG * 64 + 255) / 256, 256, 0, stream>>>(sums, cnt, out);
}

// Round 2
// 1181.010 us; speedup vs baseline: 1.2307x; 1.2307x over previous
//
#include <hip/hip_runtime.h>
#include <hip/hip_bf16.h>

#define NN 80000
#define NE 1280000
#define HID 64
#define NL 4
#define NG 256

__device__ __forceinline__ float wave_sum(float v) {
    for (int off = 32; off; off >>= 1) v += __shfl_xor(v, off, 64);
    return v;
}

// ---------------- CSR build ----------------
__global__ void k_count(const int* __restrict__ dst, int* __restrict__ cnt) {
    int e = blockIdx.x * 256 + threadIdx.x;
    if (e < NE) atomicAdd(&cnt[dst[e]], 1);
}

// inclusive scan of 256-elem chunks; writes chunk-scanned values to out, chunk totals to bsum
__global__ void k_scan1(const int* __restrict__ in, int* __restrict__ out,
                        int* __restrict__ bsum, int n) {
    __shared__ int ws[4];
    int i = blockIdx.x * 256 + threadIdx.x;
    int v = (i < n) ? in[i] : 0;
    int lane = threadIdx.x & 63, w = threadIdx.x >> 6;
    for (int off = 1; off < 64; off <<= 1) {
        int t = __shfl_up(v, off, 64);
        if (lane >= off) v += t;
    }
    if (lane == 63) ws[w] = v;
    __syncthreads();
    if (threadIdx.x == 0) {
        int acc = 0;
        for (int k = 0; k < 4; k++) { int t = ws[k]; ws[k] = acc; acc += t; }
    }
    __syncthreads();
    v += ws[w];
    if (i < n) out[i] = v;
    if (threadIdx.x == 255) bsum[blockIdx.x] = v;
}

// single-block inclusive scan over nb elements in place
__global__ void k_scan2(int* __restrict__ bsum, int nb) {
    __shared__ int ws[4];
    __shared__ int carry;
    if (threadIdx.x == 0) carry = 0;
    __syncthreads();
    for (int base = 0; base < nb; base += 256) {
        int i = base + threadIdx.x;
        int v = (i < nb) ? bsum[i] : 0;
        int lane = threadIdx.x & 63, w = threadIdx.x >> 6;
        for (int off = 1; off < 64; off <<= 1) {
            int t = __shfl_up(v, off, 64);
            if (lane >= off) v += t;
        }
        if (lane == 63) ws[w] = v;
        __syncthreads();
        if (threadIdx.x == 0) {
            int acc = carry;
            for (int k = 0; k < 4; k++) { int t = ws[k]; ws[k] = acc; acc += t; }
            carry = acc;
        }
        __syncthreads();
        v += ws[w];
        if (i < nb) bsum[i] = v;
        __syncthreads();
    }
}

// rowptr[1+i] += block offset; rowptr[0]=0   (rowptr+1 already holds chunk-scanned counts)
__global__ void k_scan3(int* __restrict__ rowptr, const int* __restrict__ bsum, int n) {
    int i = blockIdx.x * 256 + threadIdx.x;
    if (i < n) {
        int off = (blockIdx.x > 0) ? bsum[blockIdx.x - 1] : 0;
        rowptr[1 + i] += off;
    }
    if (i == 0 && blockIdx.x == 0) rowptr[0] = 0;
}

__global__ void k_fill(const int* __restrict__ src, const int* __restrict__ dst,
                       const int* __restrict__ eattr, const int* __restrict__ rowptr,
                       int* __restrict__ wofs, int2* __restrict__ csr) {
    int e = blockIdx.x * 256 + threadIdx.x;
    if (e >= NE) return;
    int d = dst[e];
    int pos = rowptr[d] + atomicAdd(&wofs[d], 1);
    int a0 = eattr[e * 3], a1 = eattr[e * 3 + 1], a2 = eattr[e * 3 + 2];
    csr[pos] = make_int2(src[e], a0 + a1 * 10 + a2 * 100);
}

// ---------------- encoders ----------------
__global__ void k_comb(const float* __restrict__ bond_emb, float* __restrict__ comb) {
    int wid = (blockIdx.x * 256 + threadIdx.x) >> 6;
    int lane = threadIdx.x & 63;
    if (wid >= 1000) return;
    int a0 = wid % 10, a1 = (wid / 10) % 10, a2 = wid / 100;
    comb[wid * 64 + lane] = bond_emb[a0 * 64 + lane] +
                            bond_emb[(10 + a1) * 64 + lane] +
                            bond_emb[(20 + a2) * 64 + lane];
}

__global__ void k_atom(const int* __restrict__ x, const float* __restrict__ atom_emb,
                       float* __restrict__ xn) {
    int wid = (blockIdx.x * 256 + threadIdx.x) >> 6;
    int lane = threadIdx.x & 63;
    if (wid >= NN) return;
    float acc = 0.f;
#pragma unroll
    for (int f = 0; f < 9; f++) {
        int idx = x[wid * 9 + f] + f * 100;
        acc += atom_emb[idx * 64 + lane];
    }
    xn[wid * 64 + lane] = acc;
}

// ---------------- per-layer ----------------
__global__ void k_prenorm(const float* __restrict__ cur, const float* __restrict__ g,
                          const float* __restrict__ b, float* __restrict__ hh) {
    int wid = (blockIdx.x * 256 + threadIdx.x) >> 6;
    int lane = threadIdx.x & 63;
    if (wid >= NN) return;
    float v = cur[(long)wid * 64 + lane];
    float mu = wave_sum(v) * (1.f / 64.f);
    float d = v - mu;
    float var = wave_sum(d * d) * (1.f / 64.f);
    float y = d * rsqrtf(var + 1e-5f) * g[lane] + b[lane];
    hh[(long)wid * 64 + lane] = fmaxf(y, 0.f);
}

// fused: online-softmax edge aggregation + root add + MLP(64->128->LN->ReLU->64) + residual
__global__ __launch_bounds__(256) void k_conv(
    const float* __restrict__ hin, const int* __restrict__ rowptr,
    const int2* __restrict__ csr, const float* __restrict__ comb,
    const float* __restrict__ t, int l,
    const float* __restrict__ W1, const float* __restrict__ b1,
    const float* __restrict__ g1, const float* __restrict__ bb1,
    const float* __restrict__ W2, const float* __restrict__ b2,
    float* __restrict__ cur, int residual) {
    int wid = (blockIdx.x * 256 + threadIdx.x) >> 6;
    int lane = threadIdx.x & 63;
    if (wid >= NN) return;
    float tl = t[l];
    int rs = rowptr[wid], re = rowptr[wid + 1];
    float mx = -INFINITY, den = 0.f, num = 0.f;
    for (int p = rs; p < re; ++p) {
        int2 sc = csr[p];
        float h = hin[(long)sc.x * 64 + lane];
        float ea = comb[sc.y * 64 + lane];
        float msg = fmaxf(h + ea, 0.f) + 1e-7f;
        float m = msg * tl;
        if (m > mx) {
            float s = __expf(mx - m);
            den *= s; num *= s; mx = m;
        }
        float e = __expf(m - mx);
        den += e;
        num += e * msg;
    }
    float o = num / (den + 1e-16f) + hin[(long)wid * 64 + lane];

    const float* W1l = W1 + (long)l * 64 * 128;
    const float* W2l = W2 + (long)l * 128 * 64;
    float a0 = b1[l * 128 + lane];
    float a1 = b1[l * 128 + 64 + lane];
    for (int k = 0; k < 64; ++k) {
        float ok = __shfl(o, k, 64);
        a0 = fmaf(ok, W1l[k * 128 + lane], a0);
        a1 = fmaf(ok, W1l[k * 128 + 64 + lane], a1);
    }
    float mu = wave_sum(a0 + a1) * (1.f / 128.f);
    float d0 = a0 - mu, d1 = a1 - mu;
    float var = wave_sum(d0 * d0 + d1 * d1) * (1.f / 128.f);
    float r = rsqrtf(var + 1e-5f);
    float m0 = fmaxf(d0 * r * g1[l * 128 + lane] + bb1[l * 128 + lane], 0.f);
    float m1 = fmaxf(d1 * r * g1[l * 128 + 64 + lane] + bb1[l * 128 + 64 + lane], 0.f);
    float acc = b2[l * 64 + lane];
    for (int j = 0; j < 64; ++j) {
        float v0 = __shfl(m0, j, 64);
        float v1 = __shfl(m1, j, 64);
        acc = fmaf(v0, W2l[j * 64 + lane], acc);
        acc = fmaf(v1, W2l[(j + 64) * 64 + lane], acc);
    }
    long oi = (long)wid * 64 + lane;
    cur[oi] = (residual ? cur[oi] : 0.f) + acc;
}

// ---------------- pooling (atomic-free, batch is sorted) ----------------
// gstart[g] = first node index of graph g; gstart[NG] = NN
__global__ void k_bounds(const int* __restrict__ batch, int* __restrict__ gstart) {
    int i = blockIdx.x * 256 + threadIdx.x;
    if (i >= NN) return;
    int b = batch[i];
    if (i == 0) {
        for (int g = 0; g <= b; ++g) gstart[g] = 0;
    } else {
        int pb = batch[i - 1];
        for (int g = pb + 1; g <= b; ++g) gstart[g] = i;
    }
    if (i == NN - 1) {
        for (int g = b + 1; g <= NG; ++g) gstart[g] = NN;
    }
}

// one block per graph: fused final LN+ReLU + mean pool, no atomics
__global__ __launch_bounds__(1024) void k_pool2(
    const float* __restrict__ cur, const int* __restrict__ gstart,
    const float* __restrict__ g, const float* __restrict__ b,
    float* __restrict__ out) {
    int gi = blockIdx.x;
    int lane = threadIdx.x & 63, w = threadIdx.x >> 6;   // 16 waves
    int s = gstart[gi], e = gstart[gi + 1];
    float gg = g[lane], bb = b[lane];
    float acc = 0.f;
    for (int n = s + w; n < e; n += 16) {
        float v = cur[(long)n * 64 + lane];
        float mu = wave_sum(v) * (1.f / 64.f);
        float d = v - mu;
        float var = wave_sum(d * d) * (1.f / 64.f);
        acc += fmaxf(d * rsqrtf(var + 1e-5f) * gg + bb, 0.f);
    }
    __shared__ float sh[16][64];
    sh[w][lane] = acc;
    __syncthreads();
    if (w == 0) {
        float tot = 0.f;
#pragma unroll
        for (int k = 0; k < 16; ++k) tot += sh[k][lane];
        out[gi * 64 + lane] = tot / fmaxf((float)(e - s), 1.f);
    }
}

extern "C" void kernel_launch(void* const* d_in, const int* in_sizes, int n_in,
                              void* d_out, int out_size, void* d_ws, size_t ws_size,
                              hipStream_t stream) {
    (void)in_sizes; (void)n_in; (void)out_size; (void)ws_size;
    const int* x         = (const int*)d_in[0];
    const int* edge_attr = (const int*)d_in[1];
    const int* src       = (const int*)d_in[2];
    const int* dst       = src + NE;
    const int* batch     = (const int*)d_in[3];
    const float* atom_emb = (const float*)d_in[4];
    const float* bond_emb = (const float*)d_in[5];
    const float* t        = (const float*)d_in[6];
    const float* W1       = (const float*)d_in[7];
    const float* b1       = (const float*)d_in[8];
    const float* g1       = (const float*)d_in[9];
    const float* bb1      = (const float*)d_in[10];
    const float* W2       = (const float*)d_in[11];
    const float* b2       = (const float*)d_in[12];
    const float* norm_g   = (const float*)d_in[13];
    const float* norm_b   = (const float*)d_in[14];
    float* out = (float*)d_out;

    size_t off = 0;
    auto alloc = [&](size_t bytes) {
        void* p = (char*)d_ws + off;
        off += (bytes + 255) & ~(size_t)255;
        return p;
    };
    int*   count  = (int*)alloc((size_t)NN * 4);
    int*   wofs   = (int*)alloc((size_t)NN * 4);
    int*   rowptr = (int*)alloc((size_t)(NN + 1) * 4);
    int*   bsum   = (int*)alloc(4096);
    int2*  csr    = (int2*)alloc((size_t)NE * 8);
    float* comb   = (float*)alloc(1000 * 64 * 4);
    float* xn     = (float*)alloc((size_t)NN * 64 * 4);
    float* hh     = (float*)alloc((size_t)NN * 64 * 4);
    float* cur    = (float*)alloc((size_t)NN * 64 * 4);
    int*   gstart = (int*)alloc((size_t)(NG + 1) * 4);

    hipMemsetAsync(count, 0, (size_t)NN * 4, stream);
    hipMemsetAsync(wofs, 0, (size_t)NN * 4, stream);

    const int EB = (NE + 255) / 256;          // 5000
    const int SB = (NN + 255) / 256;          // 313
    const int WB = (NN * 64 + 255) / 256;     // 20000 (wave-per-node blocks)

    k_count<<<EB, 256, 0, stream>>>(dst, count);
    k_scan1<<<SB, 256, 0, stream>>>(count, rowptr + 1, bsum, NN);
    k_scan2<<<1, 256, 0, stream>>>(bsum, SB);
    k_scan3<<<SB, 256, 0, stream>>>(rowptr, bsum, NN);
    k_fill<<<EB, 256, 0, stream>>>(src, dst, edge_attr, rowptr, wofs, csr);
    k_comb<<<(1000 * 64 + 255) / 256, 256, 0, stream>>>(bond_emb, comb);
    k_atom<<<WB, 256, 0, stream>>>(x, atom_emb, xn);
    k_bounds<<<SB, 256, 0, stream>>>(batch, gstart);

    // layer 0: cur = genconv(xn, 0)
    k_conv<<<WB, 256, 0, stream>>>(xn, rowptr, csr, comb, t, 0,
                                   W1, b1, g1, bb1, W2, b2, cur, 0);
    // layers 1..3: cur += genconv(relu(ln(cur, norm[l])), l)
    for (int l = 1; l < NL; ++l) {
        k_prenorm<<<WB, 256, 0, stream>>>(cur, norm_g + l * 64, norm_b + l * 64, hh);
        k_conv<<<WB, 256, 0, stream>>>(hh, rowptr, csr, comb, t, l,
                                       W1, b1, g1, bb1, W2, b2, cur, 1);
    }
    k_pool2<<<NG, 1024, 0, stream>>>(cur, gstart, norm_g, norm_b, out);
}